// Round 2
// 1070.883 us; speedup vs baseline: 1.0501x; 1.0501x over previous
//
#include <hip/hip_runtime.h>
#include <hip/hip_fp16.h>
#include <stdint.h>

typedef _Float16 f16;
typedef _Float16 f16x8 __attribute__((ext_vector_type(8)));
typedef _Float16 f16x4 __attribute__((ext_vector_type(4)));
typedef float f32x4 __attribute__((ext_vector_type(4)));

// async global->LDS, 16B per lane; LDS dest is wave-uniform base + lane*16
__device__ __forceinline__ void gload_lds16(const void* g, void* l) {
    __builtin_amdgcn_global_load_lds(
        (const __attribute__((address_space(1))) void*)g,
        (__attribute__((address_space(3))) void*)l,
        16, 0, 0);
}

// ---------------- kernel 0a: X fp32 -> f16 ----------------
__global__ __launch_bounds__(256) void convert_x(const float* __restrict__ X,
                                                 f16* __restrict__ Xh) {
    size_t i = ((size_t)blockIdx.x * 256 + threadIdx.x) * 8;
    float4 a = *(const float4*)(X + i);
    float4 b = *(const float4*)(X + i + 4);
    f16x8 o;
    o[0] = (f16)a.x; o[1] = (f16)a.y; o[2] = (f16)a.z; o[3] = (f16)a.w;
    o[4] = (f16)b.x; o[5] = (f16)b.y; o[6] = (f16)b.z; o[7] = (f16)b.w;
    *(f16x8*)(Xh + i) = o;
}

// ---------------- kernel 0b: W [K][N] fp32 -> Wt [3N][K] f16 ----------------
__global__ __launch_bounds__(1024) void transpose_w(const float* __restrict__ Wq,
                                                    const float* __restrict__ Wk,
                                                    const float* __restrict__ Wv,
                                                    f16* __restrict__ Wt) {
    __shared__ float tile[32][33];
    const int w = blockIdx.z;
    const float* W = (w == 0) ? Wq : ((w == 1) ? Wk : Wv);
    const int n0 = blockIdx.x * 32, k0 = blockIdx.y * 32;
    const int tx = threadIdx.x, ty = threadIdx.y;
    tile[ty][tx] = W[(size_t)(k0 + ty) * 1024 + n0 + tx];
    __syncthreads();
    Wt[(size_t)(w * 1024 + n0 + ty) * 1024 + k0 + tx] = (f16)tile[tx][ty];
}

// ---------------- kernel 1: QKV = X @ W + b  (m97-style 128x128 tile) -------
// A: Xh [65536][1024] f16, Bt: Wt [3072][1024] f16 (row n, contiguous k)
// Out: Q,K as [B=1024][H=16][L=64][D=64] f16 ; V stored TRANSPOSED [B][H][D][L]
__global__ __launch_bounds__(256) void qkv_gemm(const f16* __restrict__ A,
                                                const f16* __restrict__ Bt,
                                                const float* __restrict__ bq,
                                                const float* __restrict__ bk,
                                                const float* __restrict__ bv,
                                                f16* __restrict__ Out) {
    __shared__ __align__(16) f16 sA[128][32];
    __shared__ __align__(16) f16 sB[128][32];

    const int tid  = threadIdx.x;
    const int wave = tid >> 6, lane = tid & 63;
    const int quad = lane >> 4, l16 = lane & 15;
    const int m0 = blockIdx.y * 128, n0 = blockIdx.x * 128;
    const int wm = (wave & 1) * 64, wn = (wave >> 1) * 64;

    // staging: wave covers 32 rows (2 ops x 16 rows); lane i -> row i/4, col (i%4)*8
    const int srow = lane >> 2;
    const int scol = (lane & 3) * 8;
    const f16* gA = A  + (size_t)(m0 + wave * 32 + srow) * 1024 + scol;
    const f16* gB = Bt + (size_t)(n0 + wave * 32 + srow) * 1024 + scol;
    f16* lA = &sA[wave * 32][0];
    f16* lB = &sB[wave * 32][0];

    f32x4 acc[4][4] = {};

    for (int k0 = 0; k0 < 1024; k0 += 32) {
        gload_lds16(gA + k0,             lA);
        gload_lds16(gA + k0 + 16 * 1024, lA + 16 * 32);
        gload_lds16(gB + k0,             lB);
        gload_lds16(gB + k0 + 16 * 1024, lB + 16 * 32);
        __syncthreads();   // drains vmcnt before barrier

        f16x8 af[4], bf[4];
#pragma unroll
        for (int t = 0; t < 4; ++t)
            af[t] = *(const f16x8*)&sA[wm + t * 16 + l16][quad * 8];
#pragma unroll
        for (int t = 0; t < 4; ++t)
            bf[t] = *(const f16x8*)&sB[wn + t * 16 + l16][quad * 8];

#pragma unroll
        for (int mt = 0; mt < 4; ++mt)
#pragma unroll
            for (int nt = 0; nt < 4; ++nt)
                acc[mt][nt] = __builtin_amdgcn_mfma_f32_16x16x32_f16(
                    af[mt], bf[nt], acc[mt][nt], 0, 0, 0);
        __syncthreads();
    }

    // epilogue: +bias, f16 store
    const int w_idx = n0 >> 10;                 // 128 | 1024 -> block-uniform
    const float* bias = (w_idx == 0) ? bq : ((w_idx == 1) ? bk : bv);
    f16* out = Out + (size_t)w_idx * (65536UL * 1024UL);
    if (w_idx == 2) {
        // V stored transposed [b][h][d][l]; 4 consecutive l per lane -> f16x4
#pragma unroll
        for (int mt = 0; mt < 4; ++mt) {
            const int mb = m0 + wm + mt * 16 + quad * 4;
            const int b = mb >> 6, l0 = mb & 63;   // l0 % 4 == 0, b uniform over r
#pragma unroll
            for (int nt = 0; nt < 4; ++nt) {
                const int n  = n0 + wn + nt * 16 + l16;
                const int nc = n & 1023;
                const int hh = nc >> 6, d = nc & 63;
                f16x4 pk;
#pragma unroll
                for (int r = 0; r < 4; ++r)
                    pk[r] = (f16)(acc[mt][nt][r] + bias[nc]);
                *(f16x4*)&out[(((size_t)b * 16 + hh) * 64 + d) * 64 + l0] = pk;
            }
        }
    } else {
#pragma unroll
        for (int mt = 0; mt < 4; ++mt) {
#pragma unroll
            for (int r = 0; r < 4; ++r) {
                const int m = m0 + wm + mt * 16 + quad * 4 + r;
                const int b = m >> 6, l = m & 63;
#pragma unroll
                for (int nt = 0; nt < 4; ++nt) {
                    const int n  = n0 + wn + nt * 16 + l16;
                    const int nc = n & 1023;
                    const int hh = nc >> 6, d = nc & 63;
                    const float v = acc[mt][nt][r] + bias[nc];
                    out[(((size_t)b * 16 + hh) * 64 + l) * 64 + d] = (f16)v;
                }
            }
        }
    }
}

// ---------------- kernel 2: attention per (b,h) -----------------------------
// Q,K in [b][h][l][d]; V pre-transposed [b][h][d][l]. Wave-parallel softmax.
__global__ __launch_bounds__(256) void attn(const f16* __restrict__ QKV,
                                            const float* __restrict__ bias_table,
                                            float* __restrict__ outp) {
    __shared__ __align__(16) f16 sQ[64][72];
    __shared__ __align__(16) f16 sK[64][72];
    __shared__ __align__(16) f16 sVt[64][72];  // [d][l]
    __shared__ __align__(16) f16 sP[64][72];   // unnormalized probs
    __shared__ float sBias[128];

    const int bh = blockIdx.x;
    const int h  = bh & 15;
    const int tid  = threadIdx.x;
    const int wave = tid >> 6, lane = tid & 63;
    const int quad = lane >> 4, l16 = lane & 15;

    const f16* Qg = QKV + (size_t)bh * 4096;
    const f16* Kg = Qg + 67108864UL;
    const f16* Vg = Kg + 67108864UL;           // transposed layout

    if (tid < 127) sBias[tid] = bias_table[tid * 16 + h];

    // stage Q, K, Vt — all row-major coalesced f16x8, no transpose writes
#pragma unroll
    for (int j = 0; j < 2; ++j) {
        const int idx = tid + j * 256;     // 0..511 chunks of 8 f16
        const int e = idx * 8;
        const int r0 = e >> 6, c0 = e & 63;
        *(f16x8*)&sQ[r0][c0]  = *(const f16x8*)(Qg + e);
        *(f16x8*)&sK[r0][c0]  = *(const f16x8*)(Kg + e);
        *(f16x8*)&sVt[r0][c0] = *(const f16x8*)(Vg + e);
    }
    __syncthreads();

    const int ib = wave * 16 + quad * 4;   // first of 4 S/O rows this lane owns
    float inv[4];

    // S = Q K^T / 8 + rel_bias ; softmax fully in-register (16-lane shuffle)
    {
        f32x4 acc[4] = {};
#pragma unroll
        for (int k0 = 0; k0 < 64; k0 += 32) {
            f16x8 a = *(const f16x8*)&sQ[wave * 16 + l16][k0 + quad * 8];
#pragma unroll
            for (int nt = 0; nt < 4; ++nt) {
                f16x8 b = *(const f16x8*)&sK[nt * 16 + l16][k0 + quad * 8];
                acc[nt] = __builtin_amdgcn_mfma_f32_16x16x32_f16(a, b, acc[nt], 0, 0, 0);
            }
        }
        // C layout: acc[nt][r] = S[ib+r][nt*16+l16]; row ib+r lives in the 16
        // lanes sharing this quad -> reduce with shfl_xor masks 1,2,4,8.
        float sv[4][4];
        float mx[4] = {-1e30f, -1e30f, -1e30f, -1e30f};
#pragma unroll
        for (int nt = 0; nt < 4; ++nt) {
            const int j = nt * 16 + l16;
#pragma unroll
            for (int r = 0; r < 4; ++r) {
                const float s = acc[nt][r] * 0.125f + sBias[ib + r - j + 63];
                sv[nt][r] = s;
                mx[r] = fmaxf(mx[r], s);
            }
        }
#pragma unroll
        for (int off = 1; off < 16; off <<= 1)
#pragma unroll
            for (int r = 0; r < 4; ++r)
                mx[r] = fmaxf(mx[r], __shfl_xor(mx[r], off));
        float sum[4] = {0.f, 0.f, 0.f, 0.f};
#pragma unroll
        for (int nt = 0; nt < 4; ++nt)
#pragma unroll
            for (int r = 0; r < 4; ++r) {
                const float e = __expf(sv[nt][r] - mx[r]);
                sv[nt][r] = e;
                sum[r] += e;
            }
#pragma unroll
        for (int off = 1; off < 16; off <<= 1)
#pragma unroll
            for (int r = 0; r < 4; ++r)
                sum[r] += __shfl_xor(sum[r], off);
#pragma unroll
        for (int r = 0; r < 4; ++r) inv[r] = 1.0f / sum[r];
        // unnormalized P -> LDS (scalar f16, ~4-way worst case)
#pragma unroll
        for (int nt = 0; nt < 4; ++nt)
#pragma unroll
            for (int r = 0; r < 4; ++r)
                sP[ib + r][nt * 16 + l16] = (f16)sv[nt][r];
    }
    __syncthreads();

    // context = (P @ V) * inv ; A = sP[i][l], B = sVt[d][l]
    {
        f32x4 acc[4] = {};
#pragma unroll
        for (int k0 = 0; k0 < 64; k0 += 32) {
            f16x8 a = *(const f16x8*)&sP[wave * 16 + l16][k0 + quad * 8];
#pragma unroll
            for (int nt = 0; nt < 4; ++nt) {
                f16x8 b = *(const f16x8*)&sVt[nt * 16 + l16][k0 + quad * 8];
                acc[nt] = __builtin_amdgcn_mfma_f32_16x16x32_f16(a, b, acc[nt], 0, 0, 0);
            }
        }
        const int b = bh >> 4;
        float* op = outp + ((size_t)b * 64 + ib) * 1024 + h * 64;
#pragma unroll
        for (int nt = 0; nt < 4; ++nt) {
            const int d = nt * 16 + l16;
#pragma unroll
            for (int r = 0; r < 4; ++r)
                op[(size_t)r * 1024 + d] = acc[nt][r] * inv[r];
        }
    }
}

extern "C" void kernel_launch(void* const* d_in, const int* in_sizes, int n_in,
                              void* d_out, int out_size, void* d_ws, size_t ws_size,
                              hipStream_t stream) {
    const float* X          = (const float*)d_in[0];
    const float* Wq         = (const float*)d_in[1];
    const float* bq         = (const float*)d_in[2];
    const float* Wk         = (const float*)d_in[3];
    const float* bk         = (const float*)d_in[4];
    const float* Wv         = (const float*)d_in[5];
    const float* bv         = (const float*)d_in[6];
    const float* bias_table = (const float*)d_in[7];
    // d_in[8] rel_index: computed analytically (i - j + 63)
    float* out = (float*)d_out;

    // workspace layout (f16): Xh 67108864 | Wt 3145728 | QKV 3*67108864
    f16* Xh  = (f16*)d_ws;
    f16* Wt  = Xh + 67108864UL;
    f16* QKV = Wt + 3145728UL;

    convert_x<<<32768, 256, 0, stream>>>(X, Xh);
    transpose_w<<<dim3(32, 32, 3), dim3(32, 32), 0, stream>>>(Wq, Wk, Wv, Wt);
    qkv_gemm<<<dim3(24, 512), 256, 0, stream>>>(Xh, Wt, bq, bk, bv, QKV);
    attn<<<16384, 256, 0, stream>>>(QKV, bias_table, out);
}

// Round 3
// 990.423 us; speedup vs baseline: 1.1354x; 1.0812x over previous
//
#include <hip/hip_runtime.h>
#include <hip/hip_fp16.h>
#include <stdint.h>

typedef _Float16 f16;
typedef _Float16 f16x8 __attribute__((ext_vector_type(8)));
typedef _Float16 f16x4 __attribute__((ext_vector_type(4)));
typedef float f32x4 __attribute__((ext_vector_type(4)));

// async global->LDS, 16B per lane; LDS dest is wave-uniform base + lane*16
__device__ __forceinline__ void gload_lds16(const void* g, void* l) {
    __builtin_amdgcn_global_load_lds(
        (const __attribute__((address_space(1))) void*)g,
        (__attribute__((address_space(3))) void*)l,
        16, 0, 0);
}

// ---------------- kernel 0a: X fp32 -> f16 ----------------
__global__ __launch_bounds__(256) void convert_x(const float* __restrict__ X,
                                                 f16* __restrict__ Xh) {
    size_t i = ((size_t)blockIdx.x * 256 + threadIdx.x) * 8;
    float4 a = *(const float4*)(X + i);
    float4 b = *(const float4*)(X + i + 4);
    f16x8 o;
    o[0] = (f16)a.x; o[1] = (f16)a.y; o[2] = (f16)a.z; o[3] = (f16)a.w;
    o[4] = (f16)b.x; o[5] = (f16)b.y; o[6] = (f16)b.z; o[7] = (f16)b.w;
    *(f16x8*)(Xh + i) = o;
}

// ---------------- kernel 0b: W [K][N] fp32 -> Wt [3N][K] f16 ----------------
__global__ __launch_bounds__(1024) void transpose_w(const float* __restrict__ Wq,
                                                    const float* __restrict__ Wk,
                                                    const float* __restrict__ Wv,
                                                    f16* __restrict__ Wt) {
    __shared__ float tile[32][33];
    const int w = blockIdx.z;
    const float* W = (w == 0) ? Wq : ((w == 1) ? Wk : Wv);
    const int n0 = blockIdx.x * 32, k0 = blockIdx.y * 32;
    const int tx = threadIdx.x, ty = threadIdx.y;
    tile[ty][tx] = W[(size_t)(k0 + ty) * 1024 + n0 + tx];
    __syncthreads();
    Wt[(size_t)(w * 1024 + n0 + ty) * 1024 + k0 + tx] = (f16)tile[tx][ty];
}

// ---------------- kernel 1: QKV = X @ W + b  (256x256 8-phase template) -----
// A: Xh [65536][1024] f16, Bt: Wt [3072][1024] f16 (row n, contiguous k)
// Out: Q,K as [B=1024][H=16][L=64][D=64] f16 ; V stored TRANSPOSED [B][H][D][L]
// BM=BN=256, BK=64, 8 waves (2M x 4N). LDS 128KB: A/B x 2 dbuf x 2 halves.
// Swizzle: physical 16B-chunk c holds logical chunk c^(row&7); staged via
// pre-swizzled global source (linear LDS dest), read with the same XOR.
__global__ __launch_bounds__(512, 2) void qkv_gemm(const f16* __restrict__ A,
                                                   const f16* __restrict__ Bt,
                                                   const float* __restrict__ bq,
                                                   const float* __restrict__ bk,
                                                   const float* __restrict__ bv,
                                                   f16* __restrict__ Out) {
    extern __shared__ __align__(16) f16 lds[];  // 65536 f16 = 128 KiB
    // elem offsets: A(d,h) = d*16384 + h*8192 ; B(d,h) = 32768 + d*16384 + h*8192
    // within half: row pr (0..127) * 64 + chunk*8

    const int tid  = threadIdx.x;
    const int wave = tid >> 6, lane = tid & 63;
    const int quad = lane >> 4, l16 = lane & 15;
    const int wm = wave >> 2, wn = wave & 3;      // 2M x 4N wave grid

    // XCD-aware swizzle (nwg=3072, 3072%8==0), n-major: consecutive share B
    const int bid = blockIdx.x;
    const int swz = (bid & 7) * 384 + (bid >> 3);
    const int m0 = (swz & 255) * 256;
    const int n0 = (swz >> 8) * 256;

    // ---- staging address setup (pre-swizzled global source) ----
    const int sub  = lane >> 3;                 // row-in-8 within the wave's 8 rows
    const int swzc = (lane & 7) ^ sub;          // logical chunk this lane fetches
    const int stDst = wave * 512 + lane * 8;    // linear LDS dest (elems)
    const f16* gA0 = A  + (size_t)(m0 + wave * 8 + sub) * 1024 + swzc * 8;
    const f16* gB0 = Bt + (size_t)(n0 + wave * 8 + sub) * 1024 + swzc * 8;

#define STAGE_A(D, H, KT) do {                                                  \
        const f16* _g = gA0 + (H) * 65536 + (KT) * 64;                          \
        gload_lds16(_g,          &lds[(D) * 16384 + (H) * 8192 + stDst]);       \
        gload_lds16(_g + 131072, &lds[(D) * 16384 + (H) * 8192 + 4096 + stDst]);\
    } while (0)
#define STAGE_B(D, H, KT) do {                                                  \
        const f16* _g = gB0 + (H) * 131072 + (KT) * 64;                         \
        gload_lds16(_g,         &lds[32768 + (D) * 16384 + (H) * 8192 + stDst]);\
        gload_lds16(_g + 65536, &lds[32768 + (D) * 16384 + (H) * 8192 + 4096 + stDst]); \
    } while (0)

    // ---- reader address setup (swizzled chunk) ----
    const int l7  = l16 & 7;
    const int cA0 = ((0 + quad) ^ l7) * 8;      // ks=0 chunk (elems)
    const int cA1 = ((4 + quad) ^ l7) * 8;      // ks=1
    const int aRow = (wm * 64 + l16) * 64;      // A row part (within dbuf+half)
    int bOff[4];
#pragma unroll
    for (int nf = 0; nf < 4; ++nf) {
        const int pr = wn * 64 + nf * 16 + l16;           // 0..255
        bOff[nf] = (pr >> 7) * 8192 + (pr & 127) * 64;    // half + row
    }

    f32x4 acc[8][4] = {};
    f16x8 bf[4][2];

#define LOAD_A(G, V0, V1)                                                        \
    f16x8 V0 = *(const f16x8*)&lds[aIdx + ((G) >> 2) * 8192 + ((G)&3) * 1024 + cA0]; \
    f16x8 V1 = *(const f16x8*)&lds[aIdx + ((G) >> 2) * 8192 + ((G)&3) * 1024 + cA1];

#define MFMA_PAIR(G0, G1)                                                        \
    _Pragma("unroll")                                                            \
    for (int nf = 0; nf < 4; ++nf) {                                             \
        acc[G0][nf] = __builtin_amdgcn_mfma_f32_16x16x32_f16(aA0, bf[nf][0], acc[G0][nf], 0, 0, 0); \
        acc[G0][nf] = __builtin_amdgcn_mfma_f32_16x16x32_f16(aA1, bf[nf][1], acc[G0][nf], 0, 0, 0); \
        acc[G1][nf] = __builtin_amdgcn_mfma_f32_16x16x32_f16(aB0, bf[nf][0], acc[G1][nf], 0, 0, 0); \
        acc[G1][nf] = __builtin_amdgcn_mfma_f32_16x16x32_f16(aB1, bf[nf][1], acc[G1][nf], 0, 0, 0); \
    }

#define PHASE_MID()                                        \
    __builtin_amdgcn_sched_barrier(0);                     \
    __builtin_amdgcn_s_barrier();                          \
    asm volatile("s_waitcnt lgkmcnt(0)" ::: "memory");     \
    __builtin_amdgcn_sched_barrier(0);                     \
    __builtin_amdgcn_s_setprio(1);

#define PHASE_END()                                        \
    __builtin_amdgcn_s_setprio(0);                         \
    __builtin_amdgcn_sched_barrier(0);                     \
    __builtin_amdgcn_s_barrier();

#define PHASE_END_WAIT(N)                                  \
    __builtin_amdgcn_s_setprio(0);                         \
    __builtin_amdgcn_sched_barrier(0);                     \
    asm volatile("s_waitcnt vmcnt(" #N ")" ::: "memory");  \
    __builtin_amdgcn_s_barrier();

    // ---- prologue: stage T0 fully + T1 {Bh0,Bh1,Ah0}; wait until T0 landed --
    STAGE_B(0, 0, 0); STAGE_B(0, 1, 0); STAGE_A(0, 0, 0); STAGE_A(0, 1, 0);
    STAGE_B(1, 0, 1); STAGE_B(1, 1, 1); STAGE_A(1, 0, 1);
    asm volatile("s_waitcnt vmcnt(6)" ::: "memory");
    __builtin_amdgcn_s_barrier();

    // ---- main loop: 16 K-tiles, 4 phases each ----
    for (int t = 0; t < 16; ++t) {
        const int d    = t & 1;
        const int aIdx = d * 16384 + aRow;
        const int bIdx = 32768 + d * 16384;

        // q0: B-frags (8) + A groups 0,1 ; stage T(t+1) Ah1 (other dbuf)
        {
#pragma unroll
            for (int nf = 0; nf < 4; ++nf) {
                bf[nf][0] = *(const f16x8*)&lds[bIdx + bOff[nf] + cA0];
                bf[nf][1] = *(const f16x8*)&lds[bIdx + bOff[nf] + cA1];
            }
            LOAD_A(0, aA0, aA1); LOAD_A(1, aB0, aB1);
            if (t + 1 < 16) STAGE_A(d ^ 1, 1, t + 1);
            PHASE_MID();
            MFMA_PAIR(0, 1);
            PHASE_END();
        }
        // q1: A groups 2,3 ; stage T(t+2) Bh0 (tile-t B read finished at q0)
        {
            LOAD_A(2, aA0, aA1); LOAD_A(3, aB0, aB1);
            if (t + 2 < 16) STAGE_B(d, 0, t + 2);
            PHASE_MID();
            MFMA_PAIR(2, 3);
            PHASE_END();
        }
        // q2: A groups 4,5 ; stage T(t+2) Bh1
        {
            LOAD_A(4, aA0, aA1); LOAD_A(5, aB0, aB1);
            if (t + 2 < 16) STAGE_B(d, 1, t + 2);
            PHASE_MID();
            MFMA_PAIR(4, 5);
            PHASE_END();
        }
        // q3: A groups 6,7 ; stage T(t+2) Ah0 (tile-t Ah0 read finished at q1)
        // counted vmcnt: retire through T(t+1)Ah1 (leave 3 newest half-tiles)
        {
            LOAD_A(6, aA0, aA1); LOAD_A(7, aB0, aB1);
            if (t + 2 < 16) STAGE_A(d, 0, t + 2);
            PHASE_MID();
            MFMA_PAIR(6, 7);
            if (t < 14) {
                PHASE_END_WAIT(6);
            } else if (t == 14) {
                PHASE_END_WAIT(0);
            } else {
                PHASE_END();
            }
        }
    }

    // ---- epilogue: +bias, f16 store ----
    const int w_idx = n0 >> 10;                 // block-uniform (256 | 1024)
    const float* bias = (w_idx == 0) ? bq : ((w_idx == 1) ? bk : bv);
    f16* outp = Out + (size_t)w_idx * 67108864UL;
    if (w_idx == 2) {
        // V stored transposed [b][h][d][l]; 4 consecutive l per lane -> f16x4
#pragma unroll
        for (int mg = 0; mg < 8; ++mg) {
            const int mb = m0 + wm * 128 + mg * 16 + quad * 4;
            const int b = mb >> 6, l0 = mb & 63;
#pragma unroll
            for (int nf = 0; nf < 4; ++nf) {
                const int nc = (n0 + wn * 64 + nf * 16 + l16) & 1023;
                const int hh = nc >> 6, dd = nc & 63;
                f16x4 pk;
#pragma unroll
                for (int r = 0; r < 4; ++r)
                    pk[r] = (f16)(acc[mg][nf][r] + bias[nc]);
                *(f16x4*)&outp[(((size_t)b * 16 + hh) * 64 + dd) * 64 + l0] = pk;
            }
        }
    } else {
#pragma unroll
        for (int mg = 0; mg < 8; ++mg) {
#pragma unroll
            for (int r = 0; r < 4; ++r) {
                const int m = m0 + wm * 128 + mg * 16 + quad * 4 + r;
                const int b = m >> 6, l = m & 63;
#pragma unroll
                for (int nf = 0; nf < 4; ++nf) {
                    const int nc = (n0 + wn * 64 + nf * 16 + l16) & 1023;
                    const int hh = nc >> 6, dd = nc & 63;
                    const float v = acc[mg][nf][r] + bias[nc];
                    outp[(((size_t)b * 16 + hh) * 64 + l) * 64 + dd] = (f16)v;
                }
            }
        }
    }
#undef STAGE_A
#undef STAGE_B
#undef LOAD_A
#undef MFMA_PAIR
#undef PHASE_MID
#undef PHASE_END
#undef PHASE_END_WAIT
}

// ---------------- kernel 2: attention per (b,h) -----------------------------
// Q,K in [b][h][l][d]; V pre-transposed [b][h][d][l]. Wave-parallel softmax.
__global__ __launch_bounds__(256) void attn(const f16* __restrict__ QKV,
                                            const float* __restrict__ bias_table,
                                            float* __restrict__ outp) {
    __shared__ __align__(16) f16 sQ[64][72];
    __shared__ __align__(16) f16 sK[64][72];
    __shared__ __align__(16) f16 sVt[64][72];  // [d][l]
    __shared__ __align__(16) f16 sP[64][72];   // unnormalized probs
    __shared__ float sBias[128];

    const int bh = blockIdx.x;
    const int h  = bh & 15;
    const int tid  = threadIdx.x;
    const int wave = tid >> 6, lane = tid & 63;
    const int quad = lane >> 4, l16 = lane & 15;

    const f16* Qg = QKV + (size_t)bh * 4096;
    const f16* Kg = Qg + 67108864UL;
    const f16* Vg = Kg + 67108864UL;           // transposed layout

    if (tid < 127) sBias[tid] = bias_table[tid * 16 + h];

    // stage Q, K, Vt — all row-major coalesced f16x8, no transpose writes
#pragma unroll
    for (int j = 0; j < 2; ++j) {
        const int idx = tid + j * 256;     // 0..511 chunks of 8 f16
        const int e = idx * 8;
        const int r0 = e >> 6, c0 = e & 63;
        *(f16x8*)&sQ[r0][c0]  = *(const f16x8*)(Qg + e);
        *(f16x8*)&sK[r0][c0]  = *(const f16x8*)(Kg + e);
        *(f16x8*)&sVt[r0][c0] = *(const f16x8*)(Vg + e);
    }
    __syncthreads();

    const int ib = wave * 16 + quad * 4;   // first of 4 S/O rows this lane owns
    float inv[4];

    // S = Q K^T / 8 + rel_bias ; softmax fully in-register (16-lane shuffle)
    {
        f32x4 acc[4] = {};
#pragma unroll
        for (int k0 = 0; k0 < 64; k0 += 32) {
            f16x8 a = *(const f16x8*)&sQ[wave * 16 + l16][k0 + quad * 8];
#pragma unroll
            for (int nt = 0; nt < 4; ++nt) {
                f16x8 b = *(const f16x8*)&sK[nt * 16 + l16][k0 + quad * 8];
                acc[nt] = __builtin_amdgcn_mfma_f32_16x16x32_f16(a, b, acc[nt], 0, 0, 0);
            }
        }
        // C layout: acc[nt][r] = S[ib+r][nt*16+l16]; row ib+r lives in the 16
        // lanes sharing this quad -> reduce with shfl_xor masks 1,2,4,8.
        float sv[4][4];
        float mx[4] = {-1e30f, -1e30f, -1e30f, -1e30f};
#pragma unroll
        for (int nt = 0; nt < 4; ++nt) {
            const int j = nt * 16 + l16;
#pragma unroll
            for (int r = 0; r < 4; ++r) {
                const float s = acc[nt][r] * 0.125f + sBias[ib + r - j + 63];
                sv[nt][r] = s;
                mx[r] = fmaxf(mx[r], s);
            }
        }
#pragma unroll
        for (int off = 1; off < 16; off <<= 1)
#pragma unroll
            for (int r = 0; r < 4; ++r)
                mx[r] = fmaxf(mx[r], __shfl_xor(mx[r], off));
        float sum[4] = {0.f, 0.f, 0.f, 0.f};
#pragma unroll
        for (int nt = 0; nt < 4; ++nt)
#pragma unroll
            for (int r = 0; r < 4; ++r) {
                const float e = __expf(sv[nt][r] - mx[r]);
                sv[nt][r] = e;
                sum[r] += e;
            }
#pragma unroll
        for (int off = 1; off < 16; off <<= 1)
#pragma unroll
            for (int r = 0; r < 4; ++r)
                sum[r] += __shfl_xor(sum[r], off);
#pragma unroll
        for (int r = 0; r < 4; ++r) inv[r] = 1.0f / sum[r];
        // unnormalized P -> LDS (scalar f16, ~4-way worst case)
#pragma unroll
        for (int nt = 0; nt < 4; ++nt)
#pragma unroll
            for (int r = 0; r < 4; ++r)
                sP[ib + r][nt * 16 + l16] = (f16)sv[nt][r];
    }
    __syncthreads();

    // context = (P @ V) * inv ; A = sP[i][l], B = sVt[d][l]
    {
        f32x4 acc[4] = {};
#pragma unroll
        for (int k0 = 0; k0 < 64; k0 += 32) {
            f16x8 a = *(const f16x8*)&sP[wave * 16 + l16][k0 + quad * 8];
#pragma unroll
            for (int nt = 0; nt < 4; ++nt) {
                f16x8 b = *(const f16x8*)&sVt[nt * 16 + l16][k0 + quad * 8];
                acc[nt] = __builtin_amdgcn_mfma_f32_16x16x32_f16(a, b, acc[nt], 0, 0, 0);
            }
        }
        const int b = bh >> 4;
        float* op = outp + ((size_t)b * 64 + ib) * 1024 + h * 64;
#pragma unroll
        for (int nt = 0; nt < 4; ++nt) {
            const int d = nt * 16 + l16;
#pragma unroll
            for (int r = 0; r < 4; ++r)
                op[(size_t)r * 1024 + d] = acc[nt][r] * inv[r];
        }
    }
}

extern "C" void kernel_launch(void* const* d_in, const int* in_sizes, int n_in,
                              void* d_out, int out_size, void* d_ws, size_t ws_size,
                              hipStream_t stream) {
    const float* X          = (const float*)d_in[0];
    const float* Wq         = (const float*)d_in[1];
    const float* bq         = (const float*)d_in[2];
    const float* Wk         = (const float*)d_in[3];
    const float* bk         = (const float*)d_in[4];
    const float* Wv         = (const float*)d_in[5];
    const float* bv         = (const float*)d_in[6];
    const float* bias_table = (const float*)d_in[7];
    // d_in[8] rel_index: computed analytically (i - j + 63)
    float* out = (float*)d_out;

    // workspace layout (f16): Xh 67108864 | Wt 3145728 | QKV 3*67108864
    f16* Xh  = (f16*)d_ws;
    f16* Wt  = Xh + 67108864UL;
    f16* QKV = Wt + 3145728UL;

    // allow 128 KiB dynamic LDS for the 8-phase GEMM (one-time, not enqueued)
    static bool lds_cfg = false;
    if (!lds_cfg) {
        hipFuncSetAttribute((const void*)qkv_gemm,
                            hipFuncAttributeMaxDynamicSharedMemorySize, 131072);
        lds_cfg = true;
    }

    convert_x<<<32768, 256, 0, stream>>>(X, Xh);
    transpose_w<<<dim3(32, 32, 3), dim3(32, 32), 0, stream>>>(Wq, Wk, Wv, Wt);
    qkv_gemm<<<3072, 512, 131072, stream>>>(Xh, Wt, bq, bk, bv, QKV);
    attn<<<16384, 256, 0, stream>>>(QKV, bias_table, out);
}